// Round 7
// baseline (250.953 us; speedup 1.0000x reference)
//
#include <hip/hip_runtime.h>
#include <hip/hip_bf16.h>
#include <math.h>

typedef __hip_bfloat16 bf16;
typedef __attribute__((ext_vector_type(8))) short s16x8;
typedef __attribute__((ext_vector_type(4))) float f32x4;

__device__ __forceinline__ float siluf(float x) { return x / (1.f + __expf(-x)); }
__device__ __forceinline__ float bits2f(unsigned short u) {
    union { float f; unsigned i; } v; v.i = ((unsigned)u) << 16; return v.f;
}
__device__ __forceinline__ unsigned short f2bits(float f) {
    return (unsigned short)__bfloat16_as_ushort(__float2bfloat16(f));
}
__device__ __forceinline__ uint4 bmul8(uint4 g, uint4 u) {
    const unsigned short* gs = (const unsigned short*)&g;
    const unsigned short* us = (const unsigned short*)&u;
    uint4 r; unsigned short* rs = (unsigned short*)&r;
    #pragma unroll
    for (int i = 0; i < 8; i++) rs[i] = f2bits(bits2f(gs[i]) * bits2f(us[i]));
    return r;
}

// ---------------- workspace offsets (float units) ----------------
#define KFL 1024
#define OFF_UB   (768*KFL)
#define OFF_DTV  (1280*KFL)
#define OFF_BMB  (1344*KFL)
#define OFF_CMB  (2368*KFL)
#define OFF_ZGB  (3392*KFL)
#define OFF_X32  (3904*KFL)
#define OFF_X2T  (4928*KFL)
#define OFF_P    (5440*KFL)
#define OFF_YGB  (7488*KFL)
#define OFF_Z1   (8000*KFL)
#define OFF_ZNB  OFF_UB
#define OFF_QKV  OFF_BMB
#define OFF_OB   (2880*KFL)
#define OFF_Z2   OFF_P
#define OFF_ZFB  (6464*KFL)
#define OFF_SGU  OFF_BMB

// weight element offsets (bf16 elements, from ws base)
#define W_BCZX 0
#define W_OUT  393216
#define W_QKV  458752
#define W_AO   655360
#define W_GU   720896
#define W_D    1245184

// ------- tiled weight prep: fp32 [K,N] -> bf16 [N,K] via LDS transpose ----
__global__ __launch_bounds__(256) void prep_w(
    const float* __restrict__ Wx, const float* __restrict__ Wb,
    const float* __restrict__ Wc, const float* __restrict__ Wz,
    const float* __restrict__ Wo, const float* __restrict__ Wqkv,
    const float* __restrict__ Wao, const float* __restrict__ Wg,
    const float* __restrict__ Wu, const float* __restrict__ Wd,
    const float* __restrict__ U, const float* __restrict__ V,
    unsigned short* __restrict__ out)
{
    int blk = blockIdx.x;
    int tid = threadIdx.x;
    if (blk >= 304) {
        int off = blk - 304;
        const float* src; int dst, base;
        if (off < 48) { src = Wqkv; dst = W_QKV; base = off * 4096; }
        else          { src = Wao;  dst = W_AO;  base = (off - 48) * 4096; }
        #pragma unroll
        for (int i = 0; i < 16; i++) {
            int idx = base + tid + i * 256;
            out[dst + idx] = f2bits(src[idx]);
        }
        return;
    }
    __shared__ float lds[64 * 65];
    const float* src; int srcN, n0, sc0, k0, dstoff, dstK, mix = 0, t;
    if (blk < 32)       { t = blk;       src = Wb; srcN = 512;  dstoff = W_BCZX; dstK = 256;
                          n0 = (t >> 2) * 64;        sc0 = 0; k0 = (t & 3) * 64; mix = 1; }
    else if (blk < 64)  { t = blk - 32;  src = Wc; srcN = 512;  dstoff = W_BCZX; dstK = 256;
                          n0 = 512 + (t >> 2) * 64;  sc0 = (t >> 2) * 64; k0 = (t & 3) * 64; }
    else if (blk < 80)  { t = blk - 64;  src = Wz; srcN = 256;  dstoff = W_BCZX; dstK = 256;
                          n0 = 1024 + (t >> 2) * 64; sc0 = (t >> 2) * 64; k0 = (t & 3) * 64; }
    else if (blk < 96)  { t = blk - 80;  src = Wx; srcN = 256;  dstoff = W_BCZX; dstK = 256;
                          n0 = 1280 + (t >> 2) * 64; sc0 = (t >> 2) * 64; k0 = (t & 3) * 64; }
    else if (blk < 112) { t = blk - 96;  src = Wo; srcN = 256;  dstoff = W_OUT;  dstK = 256;
                          n0 = (t >> 2) * 64;        sc0 = n0; k0 = (t & 3) * 64; }
    else if (blk < 176) { t = blk - 112; src = Wg; srcN = 1024; dstoff = W_GU;   dstK = 256;
                          n0 = (t >> 2) * 64;        sc0 = n0; k0 = (t & 3) * 64; }
    else if (blk < 240) { t = blk - 176; src = Wu; srcN = 1024; dstoff = W_GU;   dstK = 256;
                          n0 = 1024 + (t >> 2) * 64; sc0 = (t >> 2) * 64; k0 = (t & 3) * 64; }
    else                { t = blk - 240; src = Wd; srcN = 256;  dstoff = W_D;    dstK = 1024;
                          n0 = (t >> 4) * 64;        sc0 = n0; k0 = (t & 15) * 64; }
    if (mix) {
        int h = n0 >> 7, scol = n0 & 127;
        float mm[4];
        #pragma unroll
        for (int g = 0; g < 4; g++) {
            float s = 0.f;
            #pragma unroll
            for (int j = 0; j < 4; j++) s += U[h * 4 + j] * V[g * 4 + j];
            mm[g] = s;
        }
        #pragma unroll
        for (int i = 0; i < 16; i++) {
            int idx = tid + i * 256;
            int kk = idx >> 6, nn = idx & 63;
            const float* row = src + (size_t)(k0 + kk) * 512 + scol + nn;
            float v = mm[0] * row[0] + mm[1] * row[128] + mm[2] * row[256] + mm[3] * row[384];
            lds[kk * 65 + nn] = v;
        }
    } else {
        #pragma unroll
        for (int i = 0; i < 16; i++) {
            int idx = tid + i * 256;
            int kk = idx >> 6, nn = idx & 63;
            lds[kk * 65 + nn] = src[(size_t)(k0 + kk) * srcN + sc0 + nn];
        }
    }
    __syncthreads();
    #pragma unroll
    for (int i = 0; i < 16; i++) {
        int idx = tid + i * 256;
        int nn = idx >> 6, kk = idx & 63;
        out[dstoff + (size_t)(n0 + nn) * dstK + k0 + kk] = f2bits(lds[kk * 65 + nn]);
    }
}

// ------- LN1 (z fp32 B,T,K,D -> u bf16 band-major) fused with dt = softplus(u@Wdt+b) --
__global__ __launch_bounds__(256) void ln1_dt_kernel(const float* __restrict__ z,
    const float* __restrict__ g, const float* __restrict__ b,
    const float* __restrict__ Wdt, const float* __restrict__ dt_bias,
    unsigned short* __restrict__ u, float4* __restrict__ dtv4)
{
    int r = blockIdx.x;
    int t = r & 255, bk = r >> 8;
    int b_ = bk >> 3, k = bk & 7;
    int src = ((b_ * 256 + t) * 8 + k) * 256;
    int d = threadIdx.x;
    float x = z[src + d];
    __shared__ float lds[4];
    __shared__ float dts[4][4];
    float v = x;
    #pragma unroll
    for (int off = 32; off; off >>= 1) v += __shfl_xor(v, off, 64);
    if ((d & 63) == 0) lds[d >> 6] = v;
    __syncthreads();
    float mean = (lds[0] + lds[1] + lds[2] + lds[3]) * (1.f / 256.f);
    __syncthreads();
    float c = x - mean;
    v = c * c;
    #pragma unroll
    for (int off = 32; off; off >>= 1) v += __shfl_xor(v, off, 64);
    if ((d & 63) == 0) lds[d >> 6] = v;
    __syncthreads();
    float var = (lds[0] + lds[1] + lds[2] + lds[3]) * (1.f / 256.f);
    float uval = c * rsqrtf(var + 1e-5f) * g[d] + b[d];
    u[r * 256 + d] = f2bits(uval);
    float4 wv = *(const float4*)(Wdt + d * 4);
    float q0 = uval * wv.x, q1 = uval * wv.y, q2 = uval * wv.z, q3 = uval * wv.w;
    #pragma unroll
    for (int off = 32; off; off >>= 1) {
        q0 += __shfl_xor(q0, off, 64);
        q1 += __shfl_xor(q1, off, 64);
        q2 += __shfl_xor(q2, off, 64);
        q3 += __shfl_xor(q3, off, 64);
    }
    if ((d & 63) == 0) {
        int w = d >> 6;
        dts[w][0] = q0; dts[w][1] = q1; dts[w][2] = q2; dts[w][3] = q3;
    }
    __syncthreads();
    if (d == 0) {
        float dv[4];
        #pragma unroll
        for (int h = 0; h < 4; h++) {
            float xx = dts[0][h] + dts[1][h] + dts[2][h] + dts[3][h] + dt_bias[h];
            dv[h] = (xx > 20.f) ? xx : log1pf(__expf(xx));
        }
        dtv4[r] = make_float4(dv[0], dv[1], dv[2], dv[3]);
    }
}

// ---------------- generic MFMA bf16 GEMM (128x128 tile, 4 waves) ----------------
__global__ __launch_bounds__(256) void mfma_gemm(
    const unsigned short* __restrict__ A, const unsigned short* __restrict__ Bt,
    const float* __restrict__ bias, const float* __restrict__ resid,
    void* __restrict__ C, int N, int K, int act, int out_bf16)
{
    __shared__ unsigned short As[128 * 40];
    __shared__ unsigned short Bs[128 * 40];
    int tid = threadIdx.x;
    int n0 = blockIdx.x * 128, m0 = blockIdx.y * 128;
    int w = tid >> 6, l = tid & 63;
    int mwave = (w >> 1) * 64, nwave = (w & 1) * 64;
    f32x4 acc[4][4] = {};
    int srow = tid >> 2, sc = (tid & 3) * 8;
    const unsigned short* Ap = A + (size_t)(m0 + srow) * K + sc;
    const unsigned short* Bp = Bt + (size_t)(n0 + srow) * K + sc;
    int lq = l & 15, lh = l >> 4, ko = lh * 8;
    for (int k0 = 0; k0 < K; k0 += 32) {
        uint4 a0 = *(const uint4*)(Ap + k0);
        uint4 a1 = *(const uint4*)(Ap + (size_t)64 * K + k0);
        uint4 b0 = *(const uint4*)(Bp + k0);
        uint4 b1 = *(const uint4*)(Bp + (size_t)64 * K + k0);
        if (k0) __syncthreads();
        *(uint4*)&As[srow * 40 + sc] = a0;
        *(uint4*)&As[(srow + 64) * 40 + sc] = a1;
        *(uint4*)&Bs[srow * 40 + sc] = b0;
        *(uint4*)&Bs[(srow + 64) * 40 + sc] = b1;
        __syncthreads();
        s16x8 bfr[4];
        #pragma unroll
        for (int nf = 0; nf < 4; nf++)
            bfr[nf] = *(const s16x8*)&Bs[(nwave + nf * 16 + lq) * 40 + ko];
        #pragma unroll
        for (int mf = 0; mf < 4; mf++) {
            s16x8 af = *(const s16x8*)&As[(mwave + mf * 16 + lq) * 40 + ko];
            #pragma unroll
            for (int nf = 0; nf < 4; nf++)
                acc[mf][nf] = __builtin_amdgcn_mfma_f32_16x16x32_bf16(af, bfr[nf], acc[mf][nf], 0, 0, 0);
        }
    }
    #pragma unroll
    for (int mf = 0; mf < 4; mf++) {
        #pragma unroll
        for (int nf = 0; nf < 4; nf++) {
            int n = n0 + nwave + nf * 16 + lq;
            float bs_ = bias ? bias[n] : 0.f;
            #pragma unroll
            for (int r = 0; r < 4; r++) {
                int m = m0 + mwave + mf * 16 + lh * 4 + r;
                float v = acc[mf][nf][r] + bs_;
                if (act) v = siluf(v);
                if (resid) v += resid[(size_t)m * N + n];
                if (out_bf16) ((unsigned short*)C)[(size_t)m * N + n] = f2bits(v);
                else          ((float*)C)[(size_t)m * N + n] = v;
            }
        }
    }
}

// ---- fused GEMM(64x256) + bias + residual + LayerNorm epilogue ----
// A [4096,256] bf16; Bt [256,256] bf16. Each block owns 64 COMPLETE rows.
// rowmap=1: A rows are band-major rb, output rows token-major rt (Wout case).
// Writes zfull (fp32, pre-LN) and znorm (bf16, post-LN).
__global__ __launch_bounds__(256) void gemm_ln(
    const unsigned short* __restrict__ A, const unsigned short* __restrict__ Bt,
    const float* __restrict__ bias, const float* __restrict__ resid,
    const float* __restrict__ g, const float* __restrict__ b,
    float* __restrict__ zfull, unsigned short* __restrict__ znorm, int rowmap)
{
    const int K = 256;
    __shared__ unsigned short As[64 * 40];
    __shared__ unsigned short Bs[256 * 40];
    __shared__ float partS[64][4], partQ[64][4];
    int tid = threadIdx.x;
    int m0 = blockIdx.x * 64;
    int w = tid >> 6, l = tid & 63;
    int nw = w * 64;
    int lq = l & 15, lh = l >> 4, ko = lh * 8;
    f32x4 acc[4][4] = {};
    int srow = tid >> 2, sc = (tid & 3) * 8;
    const unsigned short* Ap = A + (size_t)(m0 + srow) * K + sc;
    const unsigned short* Bp = Bt + (size_t)srow * K + sc;
    for (int k0 = 0; k0 < K; k0 += 32) {
        uint4 a0 = *(const uint4*)(Ap + k0);
        uint4 b0 = *(const uint4*)(Bp + k0);
        uint4 b1 = *(const uint4*)(Bp + (size_t)64 * K + k0);
        uint4 b2 = *(const uint4*)(Bp + (size_t)128 * K + k0);
        uint4 b3 = *(const uint4*)(Bp + (size_t)192 * K + k0);
        if (k0) __syncthreads();
        *(uint4*)&As[srow * 40 + sc] = a0;
        *(uint4*)&Bs[srow * 40 + sc] = b0;
        *(uint4*)&Bs[(srow + 64) * 40 + sc] = b1;
        *(uint4*)&Bs[(srow + 128) * 40 + sc] = b2;
        *(uint4*)&Bs[(srow + 192) * 40 + sc] = b3;
        __syncthreads();
        s16x8 bfr[4];
        #pragma unroll
        for (int nf = 0; nf < 4; nf++)
            bfr[nf] = *(const s16x8*)&Bs[(nw + nf * 16 + lq) * 40 + ko];
        #pragma unroll
        for (int mf = 0; mf < 4; mf++) {
            s16x8 af = *(const s16x8*)&As[(mf * 16 + lq) * 40 + ko];
            #pragma unroll
            for (int nf = 0; nf < 4; nf++)
                acc[mf][nf] = __builtin_amdgcn_mfma_f32_16x16x32_bf16(af, bfr[nf], acc[mf][nf], 0, 0, 0);
        }
    }
    // bias + residual, in place; compute per-row partial sums
    float bv[4];
    #pragma unroll
    for (int nf = 0; nf < 4; nf++) bv[nf] = bias ? bias[nw + nf * 16 + lq] : 0.f;
    int orow[4][4];
    #pragma unroll
    for (int mf = 0; mf < 4; mf++) {
        #pragma unroll
        for (int r = 0; r < 4; r++) {
            int rb = m0 + mf * 16 + lh * 4 + r;
            if (rowmap) {
                int bk = rb >> 8, t = rb & 255;
                orow[mf][r] = ((bk >> 3) * 256 + t) * 8 + (bk & 7);
            } else orow[mf][r] = rb;
        }
    }
    #pragma unroll
    for (int mf = 0; mf < 4; mf++) {
        #pragma unroll
        for (int r = 0; r < 4; r++) {
            float s = 0.f, q = 0.f;
            #pragma unroll
            for (int nf = 0; nf < 4; nf++) {
                float v = acc[mf][nf][r] + bv[nf]
                        + resid[(size_t)orow[mf][r] * 256 + nw + nf * 16 + lq];
                acc[mf][nf][r] = v;
                s += v; q += v * v;
            }
            #pragma unroll
            for (int off = 1; off < 16; off <<= 1) {
                s += __shfl_xor(s, off, 64);
                q += __shfl_xor(q, off, 64);
            }
            if (lq == 0) {
                int row = mf * 16 + lh * 4 + r;
                partS[row][w] = s; partQ[row][w] = q;
            }
        }
    }
    __syncthreads();
    float gv[4], bbv[4];
    #pragma unroll
    for (int nf = 0; nf < 4; nf++) {
        gv[nf] = g[nw + nf * 16 + lq];
        bbv[nf] = b[nw + nf * 16 + lq];
    }
    #pragma unroll
    for (int mf = 0; mf < 4; mf++) {
        #pragma unroll
        for (int r = 0; r < 4; r++) {
            int row = mf * 16 + lh * 4 + r;
            float sum = partS[row][0] + partS[row][1] + partS[row][2] + partS[row][3];
            float sq  = partQ[row][0] + partQ[row][1] + partQ[row][2] + partQ[row][3];
            float mean = sum * (1.f / 256.f);
            float var = sq * (1.f / 256.f) - mean * mean;
            float rstd = rsqrtf(var + 1e-5f);
            size_t ro = (size_t)orow[mf][r] * 256;
            #pragma unroll
            for (int nf = 0; nf < 4; nf++) {
                int n = nw + nf * 16 + lq;
                float v = acc[mf][nf][r];
                zfull[ro + n] = v;
                znorm[ro + n] = f2bits((v - mean) * rstd * gv[nf] + bbv[nf]);
            }
        }
    }
}

// ---------------- mega GEMM BCZX: N=1536, segmented epilogue ----------------
__global__ __launch_bounds__(256) void gemm_bczx(
    const unsigned short* __restrict__ A, const unsigned short* __restrict__ Bt,
    unsigned short* __restrict__ bmb, unsigned short* __restrict__ cmb,
    unsigned short* __restrict__ zgb, float* __restrict__ x32)
{
    __shared__ unsigned short As[128 * 40];
    __shared__ unsigned short Bs[128 * 40];
    const int K = 256;
    int tid = threadIdx.x;
    int n0 = blockIdx.x * 128, m0 = blockIdx.y * 128;
    int w = tid >> 6, l = tid & 63;
    int mwave = (w >> 1) * 64, nwave = (w & 1) * 64;
    f32x4 acc[4][4] = {};
    int srow = tid >> 2, sc = (tid & 3) * 8;
    const unsigned short* Ap = A + (size_t)(m0 + srow) * K + sc;
    const unsigned short* Bp = Bt + (size_t)(n0 + srow) * K + sc;
    int lq = l & 15, lh = l >> 4, ko = lh * 8;
    for (int k0 = 0; k0 < K; k0 += 32) {
        uint4 a0 = *(const uint4*)(Ap + k0);
        uint4 a1 = *(const uint4*)(Ap + (size_t)64 * K + k0);
        uint4 b0 = *(const uint4*)(Bp + k0);
        uint4 b1 = *(const uint4*)(Bp + (size_t)64 * K + k0);
        if (k0) __syncthreads();
        *(uint4*)&As[srow * 40 + sc] = a0;
        *(uint4*)&As[(srow + 64) * 40 + sc] = a1;
        *(uint4*)&Bs[srow * 40 + sc] = b0;
        *(uint4*)&Bs[(srow + 64) * 40 + sc] = b1;
        __syncthreads();
        s16x8 bfr[4];
        #pragma unroll
        for (int nf = 0; nf < 4; nf++)
            bfr[nf] = *(const s16x8*)&Bs[(nwave + nf * 16 + lq) * 40 + ko];
        #pragma unroll
        for (int mf = 0; mf < 4; mf++) {
            s16x8 af = *(const s16x8*)&As[(mwave + mf * 16 + lq) * 40 + ko];
            #pragma unroll
            for (int nf = 0; nf < 4; nf++)
                acc[mf][nf] = __builtin_amdgcn_mfma_f32_16x16x32_bf16(af, bfr[nf], acc[mf][nf], 0, 0, 0);
        }
    }
    #pragma unroll
    for (int mf = 0; mf < 4; mf++) {
        #pragma unroll
        for (int nf = 0; nf < 4; nf++) {
            int n = n0 + nwave + nf * 16 + lq;
            #pragma unroll
            for (int r = 0; r < 4; r++) {
                int m = m0 + mwave + mf * 16 + lh * 4 + r;
                float v = acc[mf][nf][r];
                if (n < 512)       bmb[(size_t)m * 512 + n] = f2bits(v);
                else if (n < 1024) cmb[(size_t)m * 512 + (n - 512)] = f2bits(v);
                else if (n < 1280) zgb[(size_t)m * 256 + (n - 1024)] = f2bits(siluf(v));
                else               x32[(size_t)m * 256 + (n - 1280)] = v;
            }
        }
    }
}

// ---------------- mega GEMM GU: N=2048, silu on first half ----------------
__global__ __launch_bounds__(256) void gemm_gu(
    const unsigned short* __restrict__ A, const unsigned short* __restrict__ Bt,
    unsigned short* __restrict__ sgu)
{
    __shared__ unsigned short As[128 * 40];
    __shared__ unsigned short Bs[128 * 40];
    const int K = 256;
    int tid = threadIdx.x;
    int n0 = blockIdx.x * 128, m0 = blockIdx.y * 128;
    int w = tid >> 6, l = tid & 63;
    int mwave = (w >> 1) * 64, nwave = (w & 1) * 64;
    f32x4 acc[4][4] = {};
    int srow = tid >> 2, sc = (tid & 3) * 8;
    const unsigned short* Ap = A + (size_t)(m0 + srow) * K + sc;
    const unsigned short* Bp = Bt + (size_t)(n0 + srow) * K + sc;
    int lq = l & 15, lh = l >> 4, ko = lh * 8;
    for (int k0 = 0; k0 < K; k0 += 32) {
        uint4 a0 = *(const uint4*)(Ap + k0);
        uint4 a1 = *(const uint4*)(Ap + (size_t)64 * K + k0);
        uint4 b0 = *(const uint4*)(Bp + k0);
        uint4 b1 = *(const uint4*)(Bp + (size_t)64 * K + k0);
        if (k0) __syncthreads();
        *(uint4*)&As[srow * 40 + sc] = a0;
        *(uint4*)&As[(srow + 64) * 40 + sc] = a1;
        *(uint4*)&Bs[srow * 40 + sc] = b0;
        *(uint4*)&Bs[(srow + 64) * 40 + sc] = b1;
        __syncthreads();
        s16x8 bfr[4];
        #pragma unroll
        for (int nf = 0; nf < 4; nf++)
            bfr[nf] = *(const s16x8*)&Bs[(nwave + nf * 16 + lq) * 40 + ko];
        #pragma unroll
        for (int mf = 0; mf < 4; mf++) {
            s16x8 af = *(const s16x8*)&As[(mwave + mf * 16 + lq) * 40 + ko];
            #pragma unroll
            for (int nf = 0; nf < 4; nf++)
                acc[mf][nf] = __builtin_amdgcn_mfma_f32_16x16x32_bf16(af, bfr[nf], acc[mf][nf], 0, 0, 0);
        }
    }
    #pragma unroll
    for (int mf = 0; mf < 4; mf++) {
        #pragma unroll
        for (int nf = 0; nf < 4; nf++) {
            int n = n0 + nwave + nf * 16 + lq;
            #pragma unroll
            for (int r = 0; r < 4; r++) {
                int m = m0 + mwave + mf * 16 + lh * 4 + r;
                float v = acc[mf][nf][r];
                if (n < 1024) v = siluf(v);
                sgu[(size_t)m * 2048 + n] = f2bits(v);
            }
        }
    }
}

// ------- gemm_d2 (64x64): out = (silu(G)*U) @ Wd^T + resid -------
__global__ __launch_bounds__(256) void gemm_d2(
    const unsigned short* __restrict__ sgu, const unsigned short* __restrict__ Bt,
    const float* __restrict__ resid, float* __restrict__ out)
{
    __shared__ unsigned short As[64 * 40];
    __shared__ unsigned short Bs[64 * 40];
    const int K = 1024, N = 256;
    int tid = threadIdx.x;
    int n0 = blockIdx.x * 64, m0 = blockIdx.y * 64;
    int w = tid >> 6, l = tid & 63;
    int mw = (w >> 1) * 32, nw = (w & 1) * 32;
    f32x4 acc[2][2] = {};
    int srow = tid >> 2, sc = (tid & 3) * 8;
    const unsigned short* Ag = sgu + (size_t)(m0 + srow) * 2048 + sc;
    const unsigned short* Bp = Bt + (size_t)(n0 + srow) * K + sc;
    int lq = l & 15, lh = l >> 4, ko = lh * 8;
    for (int k0 = 0; k0 < K; k0 += 32) {
        uint4 a0 = bmul8(*(const uint4*)(Ag + k0), *(const uint4*)(Ag + 1024 + k0));
        uint4 b0 = *(const uint4*)(Bp + k0);
        if (k0) __syncthreads();
        *(uint4*)&As[srow * 40 + sc] = a0;
        *(uint4*)&Bs[srow * 40 + sc] = b0;
        __syncthreads();
        s16x8 bfr[2];
        #pragma unroll
        for (int nf = 0; nf < 2; nf++)
            bfr[nf] = *(const s16x8*)&Bs[(nw + nf * 16 + lq) * 40 + ko];
        #pragma unroll
        for (int mf = 0; mf < 2; mf++) {
            s16x8 af = *(const s16x8*)&As[(mw + mf * 16 + lq) * 40 + ko];
            #pragma unroll
            for (int nf = 0; nf < 2; nf++)
                acc[mf][nf] = __builtin_amdgcn_mfma_f32_16x16x32_bf16(af, bfr[nf], acc[mf][nf], 0, 0, 0);
        }
    }
    #pragma unroll
    for (int mf = 0; mf < 2; mf++) {
        #pragma unroll
        for (int nf = 0; nf < 2; nf++) {
            int n = n0 + nw + nf * 16 + lq;
            #pragma unroll
            for (int r = 0; r < 4; r++) {
                int m = m0 + mw + mf * 16 + lh * 4 + r;
                out[(size_t)m * N + n] = acc[mf][nf][r] + resid[(size_t)m * N + n];
            }
        }
    }
}

// ------- causal conv (k=4) + silu + transpose: x32 [r][d] -> x2t [bh*64+p][t] -------
__global__ __launch_bounds__(256) void conv_t_kernel(const float* __restrict__ x32,
    const float* __restrict__ w, unsigned short* __restrict__ x2t)
{
    int bhid = blockIdx.x >> 2, tt = blockIdx.x & 3;
    int bk = bhid >> 2, h = bhid & 3;
    int t0 = tt * 64;
    int tid = threadIdx.x;
    __shared__ float tile[67 * 65];
    #pragma unroll
    for (int i = 0; i < 17; i++) {
        int idx = tid + i * 256;
        if (idx < 67 * 64) {
            int tr = idx >> 6, dd = idx & 63;
            int t = t0 - 3 + tr;
            tile[tr * 65 + dd] = (t >= 0) ? x32[(size_t)(bk * 256 + t) * 256 + h * 64 + dd] : 0.f;
        }
    }
    __syncthreads();
    int wv_ = tid >> 6, lt = tid & 63;
    #pragma unroll 4
    for (int pi = 0; pi < 16; pi++) {
        int p = wv_ * 16 + pi;
        float4 wv = *(const float4*)(w + (h * 64 + p) * 4);
        float acc = tile[lt * 65 + p] * wv.x + tile[(lt + 1) * 65 + p] * wv.y +
                    tile[(lt + 2) * 65 + p] * wv.z + tile[(lt + 3) * 65 + p] * wv.w;
        x2t[(size_t)(bhid * 64 + p) * 256 + t0 + lt] = f2bits(siluf(acc));
    }
}

// ------- batched S = C @ B^T with INLINE cumsum + decay-mask epilogue -> P bf16 -------
// grid (3, 64): blockIdx.x -> (bx,by) in {(0,0),(0,1),(1,1)} (lower triangle only)
__global__ __launch_bounds__(256) void gemm_s(
    const unsigned short* __restrict__ cmb, const unsigned short* __restrict__ bmb,
    const float4* __restrict__ dtv4, const float* __restrict__ A_log,
    const float* __restrict__ theta, unsigned short* __restrict__ P)
{
    int map = blockIdx.x;
    int bx = (map == 2) ? 1 : 0;
    int by = (map == 0) ? 0 : 1;
    int bh = blockIdx.y;
    int bk = bh >> 2, h = bh & 3;
    int tid = threadIdx.x;
    __shared__ float mAs[256], phs[256], dss[256];
    {
        float4 dv = dtv4[bk * 256 + tid];
        float dth = (h == 0) ? dv.x : (h == 1) ? dv.y : (h == 2) ? dv.z : dv.w;
        float Ah = -__expf(A_log[h]);
        float th = theta[h];
        dss[tid] = dth;
        mAs[tid] = dth * Ah;
        phs[tid] = dth * th;
        __syncthreads();
        for (int off = 1; off < 256; off <<= 1) {
            float a = 0.f, p = 0.f;
            int use = (tid >= off);
            if (use) { a = mAs[tid - off]; p = phs[tid - off]; }
            __syncthreads();
            if (use) { mAs[tid] += a; phs[tid] += p; }
            __syncthreads();
        }
    }
    int w = tid >> 6, l = tid & 63;
    int mwave = (w >> 1) * 64, nwave = (w & 1) * 64;
    int lq = l & 15, lh = l >> 4, ko = lh * 8;
    unsigned short* Pout = P + (size_t)bh * 65536;
    __shared__ unsigned short As[128 * 40];
    __shared__ unsigned short Bs[128 * 40];
    f32x4 acc[4][4] = {};
    int srow = tid >> 2, sc = (tid & 3) * 8;
    const unsigned short* Ap = cmb + (size_t)(bk * 256 + by * 128 + srow) * 512 + h * 128 + sc;
    const unsigned short* Bp = bmb + (size_t)(bk * 256 + bx * 128 + srow) * 512 + h * 128 + sc;
    for (int k0 = 0; k0 < 128; k0 += 32) {
        uint4 a0 = *(const uint4*)(Ap + k0);
        uint4 a1 = *(const uint4*)(Ap + (size_t)64 * 512 + k0);
        uint4 b0 = *(const uint4*)(Bp + k0);
        uint4 b1 = *(const uint4*)(Bp + (size_t)64 * 512 + k0);
        __syncthreads();
        *(uint4*)&As[srow * 40 + sc] = a0;
        *(uint4*)&As[(srow + 64) * 40 + sc] = a1;
        *(uint4*)&Bs[srow * 40 + sc] = b0;
        *(uint4*)&Bs[(srow + 64) * 40 + sc] = b1;
        __syncthreads();
        s16x8 bfr[4];
        #pragma unroll
        for (int nf = 0; nf < 4; nf++)
            bfr[nf] = *(const s16x8*)&Bs[(nwave + nf * 16 + lq) * 40 + ko];
        #pragma unroll
        for (int mf = 0; mf < 4; mf++) {
            s16x8 af = *(const s16x8*)&As[(mwave + mf * 16 + lq) * 40 + ko];
            #pragma unroll
            for (int nf = 0; nf < 4; nf++)
                acc[mf][nf] = __builtin_amdgcn_mfma_f32_16x16x32_bf16(af, bfr[nf], acc[mf][nf], 0, 0, 0);
        }
    }
    #pragma unroll
    for (int mf = 0; mf < 4; mf++) {
        float tmv[4], tpv[4]; int tg[4];
        #pragma unroll
        for (int r = 0; r < 4; r++) {
            tg[r] = by * 128 + mwave + mf * 16 + lh * 4 + r;
            tmv[r] = mAs[tg[r]];
            tpv[r] = phs[tg[r]];
        }
        #pragma unroll
        for (int nf = 0; nf < 4; nf++) {
            int s = bx * 128 + nwave + nf * 16 + lq;
            float ms = mAs[s];
            float ps = phs[s];
            float ds = dss[s];
            #pragma unroll
            for (int r = 0; r < 4; r++) {
                float wgt = (s <= tg[r])
                    ? __expf(tmv[r] - ms) * __cosf(tpv[r] - ps) * ds : 0.f;
                Pout[tg[r] * 256 + s] = f2bits(acc[mf][nf][r] * wgt);
            }
        }
    }
}

// ------- batched Y = P @ X^T (64x64 tiles, triangular K-clip) + skip+gate -> ygb -----
__global__ __launch_bounds__(256) void gemm_y(
    const unsigned short* __restrict__ P, const unsigned short* __restrict__ x2t,
    const unsigned short* __restrict__ zgb, const float* __restrict__ Dsk,
    unsigned short* __restrict__ ygb)
{
    int by = blockIdx.x, bh = blockIdx.y;
    int bk = bh >> 2, h = bh & 3;
    int tid = threadIdx.x;
    int w = tid >> 6, l = tid & 63;
    int mw = (w >> 1) * 32, nw = (w & 1) * 32;
    int lq = l & 15, lh = l >> 4, ko = lh * 8;
    __shared__ unsigned short As[64 * 40];
    __shared__ unsigned short Bs[64 * 40];
    f32x4 acc[2][2] = {};
    int srow = tid >> 2, sc = (tid & 3) * 8;
    const unsigned short* Ap = P + (size_t)bh * 65536 + (size_t)(by * 64 + srow) * 256 + sc;
    const unsigned short* Bp = x2t + (size_t)bh * 16384 + (size_t)srow * 256 + sc;
    int kmax = (by + 1) * 64; if (kmax > 256) kmax = 256;
    for (int k0 = 0; k0 < kmax; k0 += 32) {
        uint4 a0 = *(const uint4*)(Ap + k0);
        uint4 b0 = *(const uint4*)(Bp + k0);
        if (k0) __syncthreads();
        *(uint4*)&As[srow * 40 + sc] = a0;
        *(uint4*)&Bs[srow * 40 + sc] = b0;
        __syncthreads();
        s16x8 bfr[2];
        #pragma unroll
        for (int nf = 0; nf < 2; nf++)
            bfr[nf] = *(const s16x8*)&Bs[(nw + nf * 16 + lq) * 40 + ko];
        #pragma unroll
        for (int mf = 0; mf < 2; mf++) {
            s16x8 af = *(const s16x8*)&As[(mw + mf * 16 + lq) * 40 + ko];
            #pragma unroll
            for (int nf = 0; nf < 2; nf++)
                acc[mf][nf] = __builtin_amdgcn_mfma_f32_16x16x32_bf16(af, bfr[nf], acc[mf][nf], 0, 0, 0);
        }
    }
    float dsk = Dsk[h];
    #pragma unroll
    for (int mf = 0; mf < 2; mf++) {
        #pragma unroll
        for (int nf = 0; nf < 2; nf++) {
            int p = nw + nf * 16 + lq;
            #pragma unroll
            for (int r = 0; r < 4; r++) {
                int t = by * 64 + mw + mf * 16 + lh * 4 + r;
                float xv = bits2f(x2t[(size_t)bh * 16384 + p * 256 + t]);
                float zg = bits2f(zgb[(size_t)(bk * 256 + t) * 256 + h * 64 + p]);
                ygb[(size_t)(bk * 256 + t) * 256 + h * 64 + p] =
                    f2bits((acc[mf][nf][r] + dsk * xv) * zg);
            }
        }
    }
}

// ---------------- windowed attention (bf16 in/out) ----------------
__global__ __launch_bounds__(256) void attn_kernel(const unsigned short* __restrict__ qkv,
    unsigned short* __restrict__ o)
{
    int m = blockIdx.x >> 1, w = blockIdx.x & 1;
    int tid = threadIdx.x;
    int h = tid >> 6, d = tid & 63;
    __shared__ float qs[4][256], ks[4][256], vs[4][256];
    #pragma unroll
    for (int j = 0; j < 4; j++) {
        int row = m * 8 + w * 4 + j;
        int base = row * 768;
        qs[j][tid] = bits2f(qkv[base + tid]);
        ks[j][tid] = bits2f(qkv[base + 256 + tid]);
        vs[j][tid] = bits2f(qkv[base + 512 + tid]);
    }
    __syncthreads();
    float sc[4][4];
    #pragma unroll
    for (int qi = 0; qi < 4; qi++)
        #pragma unroll
        for (int ki = 0; ki < 4; ki++) {
            float v = qs[qi][h * 64 + d] * ks[ki][h * 64 + d];
            #pragma unroll
            for (int off = 32; off; off >>= 1) v += __shfl_xor(v, off, 64);
            sc[qi][ki] = v * 0.125f;
        }
    #pragma unroll
    for (int qi = 0; qi < 4; qi++) {
        float mx = fmaxf(fmaxf(sc[qi][0], sc[qi][1]), fmaxf(sc[qi][2], sc[qi][3]));
        float e0 = __expf(sc[qi][0] - mx), e1 = __expf(sc[qi][1] - mx);
        float e2 = __expf(sc[qi][2] - mx), e3 = __expf(sc[qi][3] - mx);
        float inv = 1.f / (e0 + e1 + e2 + e3);
        float ov = (e0 * vs[0][h * 64 + d] + e1 * vs[1][h * 64 + d] +
                    e2 * vs[2][h * 64 + d] + e3 * vs[3][h * 64 + d]) * inv;
        o[(m * 8 + w * 4 + qi) * 256 + h * 64 + d] = f2bits(ov);
    }
}

extern "C" void kernel_launch(void* const* d_in, const int* in_sizes, int n_in,
                              void* d_out, int out_size, void* d_ws, size_t ws_size,
                              hipStream_t stream)
{
    const float* z         = (const float*)d_in[0];
    const float* ln1_g     = (const float*)d_in[1];
    const float* ln1_b     = (const float*)d_in[2];
    const float* Wx        = (const float*)d_in[3];
    const float* conv_w    = (const float*)d_in[4];
    const float* Wz        = (const float*)d_in[5];
    const float* Wb        = (const float*)d_in[6];
    const float* Wc        = (const float*)d_in[7];
    const float* Wdt       = (const float*)d_in[8];
    const float* dt_bias   = (const float*)d_in[9];
    const float* A_log     = (const float*)d_in[10];
    const float* theta     = (const float*)d_in[11];
    const float* D_skip    = (const float*)d_in[12];
    const float* mimo_U    = (const float*)d_in[13];
    const float* mimo_V    = (const float*)d_in[14];
    const float* Wout      = (const float*)d_in[15];
    const float* ln2_g     = (const float*)d_in[16];
    const float* ln2_b     = (const float*)d_in[17];
    const float* attn_in_w = (const float*)d_in[18];
    const float* attn_in_b = (const float*)d_in[19];
    const float* attn_out_w= (const float*)d_in[20];
    const float* attn_out_b= (const float*)d_in[21];
    const float* ln3_g     = (const float*)d_in[22];
    const float* ln3_b     = (const float*)d_in[23];
    const float* Wg        = (const float*)d_in[24];
    const float* Wu        = (const float*)d_in[25];
    const float* Wd        = (const float*)d_in[26];

    float* W = (float*)d_ws;
    unsigned short* wts = (unsigned short*)W;
    unsigned short* ub  = (unsigned short*)(W + OFF_UB);
    float4* dtv4        = (float4*)(W + OFF_DTV);
    unsigned short* bmb = (unsigned short*)(W + OFF_BMB);
    unsigned short* cmb = (unsigned short*)(W + OFF_CMB);
    unsigned short* zgb = (unsigned short*)(W + OFF_ZGB);
    float* x32          = W + OFF_X32;
    unsigned short* x2t = (unsigned short*)(W + OFF_X2T);
    unsigned short* pbuf= (unsigned short*)(W + OFF_P);
    unsigned short* ygb = (unsigned short*)(W + OFF_YGB);
    float* z1           = W + OFF_Z1;
    unsigned short* znb = (unsigned short*)(W + OFF_ZNB);
    unsigned short* qkvb= (unsigned short*)(W + OFF_QKV);
    unsigned short* ob  = (unsigned short*)(W + OFF_OB);
    float* z2           = W + OFF_Z2;
    unsigned short* zfb = (unsigned short*)(W + OFF_ZFB);
    unsigned short* sgu = (unsigned short*)(W + OFF_SGU);

    prep_w<<<368, 256, 0, stream>>>(Wx, Wb, Wc, Wz, Wout, attn_in_w, attn_out_w,
                                    Wg, Wu, Wd, mimo_U, mimo_V, wts);
    // ---------------- (a) intra-band Mamba3 (GEMM-ized scan) ----------------
    ln1_dt_kernel<<<4096, 256, 0, stream>>>(z, ln1_g, ln1_b, Wdt, dt_bias, ub, dtv4);
    gemm_bczx<<<dim3(12, 32), 256, 0, stream>>>(ub, wts + W_BCZX, bmb, cmb, zgb, x32);
    conv_t_kernel<<<256, 256, 0, stream>>>(x32, conv_w, x2t);
    gemm_s<<<dim3(3, 64), 256, 0, stream>>>(cmb, bmb, dtv4, A_log, theta, pbuf);
    gemm_y<<<dim3(4, 64), 256, 0, stream>>>(pbuf, x2t, zgb, D_skip, ygb);
    gemm_ln<<<64, 256, 0, stream>>>(ygb, wts + W_OUT, nullptr, z, ln2_g, ln2_b,
                                    z1, znb, 1);
    // ---------------- (b) inter-band windowed attention ----------------
    mfma_gemm<<<dim3(6, 32), 256, 0, stream>>>(znb, wts + W_QKV, attn_in_b, nullptr, qkvb, 768, 256, 0, 1);
    attn_kernel<<<1024, 256, 0, stream>>>(qkvb, ob);
    gemm_ln<<<64, 256, 0, stream>>>(ob, wts + W_AO, attn_out_b, z1, ln3_g, ln3_b,
                                    z2, zfb, 0);
    // ---------------- (c) SwiGLU FFN ----------------
    gemm_gu<<<dim3(16, 32), 256, 0, stream>>>(zfb, wts + W_GU, sgu);
    gemm_d2<<<dim3(4, 64), 256, 0, stream>>>(sgu, wts + W_D, z2, (float*)d_out);
}

// Round 8
// 214.131 us; speedup vs baseline: 1.1720x; 1.1720x over previous
//
#include <hip/hip_runtime.h>
#include <hip/hip_bf16.h>
#include <math.h>

typedef __hip_bfloat16 bf16;
typedef __attribute__((ext_vector_type(8))) short s16x8;
typedef __attribute__((ext_vector_type(4))) float f32x4;

__device__ __forceinline__ float siluf(float x) { return x / (1.f + __expf(-x)); }
__device__ __forceinline__ float bits2f(unsigned short u) {
    union { float f; unsigned i; } v; v.i = ((unsigned)u) << 16; return v.f;
}
__device__ __forceinline__ unsigned short f2bits(float f) {
    return (unsigned short)__bfloat16_as_ushort(__float2bfloat16(f));
}

// ---------------- workspace offsets (float units) ----------------
#define KFL 1024
#define OFF_UB   (768*KFL)
#define OFF_DTV  (1280*KFL)
#define OFF_BMB  (1344*KFL)
#define OFF_CMB  (2368*KFL)
#define OFF_ZGB  (3392*KFL)
#define OFF_XB   (3904*KFL)
#define OFF_X2T  (4928*KFL)
#define OFF_P    (5440*KFL)
#define OFF_YGB  (7488*KFL)
#define OFF_Z1   (8000*KFL)
#define OFF_ZNB  OFF_UB
#define OFF_QKV  OFF_BMB
#define OFF_OB   (2880*KFL)
#define OFF_Z2   OFF_P
#define OFF_ZFB  (6464*KFL)
#define OFF_GG   OFF_BMB

// weight element offsets (bf16 elements, from ws base)
#define W_BCZX 0
#define W_OUT  393216
#define W_QKV  458752
#define W_AO   655360
#define W_GU   720896
#define W_D    1245184

// ======== combo1: weight prep (blocks 0..367) + LN1+dt (blocks 368..4463) ========
__global__ __launch_bounds__(256) void prep_ln1_kernel(
    const float* __restrict__ Wx, const float* __restrict__ Wb,
    const float* __restrict__ Wc, const float* __restrict__ Wz,
    const float* __restrict__ Wo, const float* __restrict__ Wqkv,
    const float* __restrict__ Wao, const float* __restrict__ Wg,
    const float* __restrict__ Wu, const float* __restrict__ Wd,
    const float* __restrict__ U, const float* __restrict__ V,
    unsigned short* __restrict__ wout,
    const float* __restrict__ z, const float* __restrict__ g1,
    const float* __restrict__ b1, const float* __restrict__ Wdt,
    const float* __restrict__ dt_bias,
    unsigned short* __restrict__ u, float4* __restrict__ dtv4)
{
    __shared__ __align__(16) float smem[64 * 65];
    int blk = blockIdx.x;
    int tid = threadIdx.x;
    if (blk < 368) {
        if (blk >= 304) {
            int off = blk - 304;
            const float* src; int dst, base;
            if (off < 48) { src = Wqkv; dst = W_QKV; base = off * 4096; }
            else          { src = Wao;  dst = W_AO;  base = (off - 48) * 4096; }
            #pragma unroll
            for (int i = 0; i < 16; i++) {
                int idx = base + tid + i * 256;
                wout[dst + idx] = f2bits(src[idx]);
            }
            return;
        }
        float* lds = smem;
        const float* src; int srcN, n0, sc0, k0, dstoff, dstK, mix = 0, t;
        if (blk < 32)       { t = blk;       src = Wb; srcN = 512;  dstoff = W_BCZX; dstK = 256;
                              n0 = (t >> 2) * 64;        sc0 = 0; k0 = (t & 3) * 64; mix = 1; }
        else if (blk < 64)  { t = blk - 32;  src = Wc; srcN = 512;  dstoff = W_BCZX; dstK = 256;
                              n0 = 512 + (t >> 2) * 64;  sc0 = (t >> 2) * 64; k0 = (t & 3) * 64; }
        else if (blk < 80)  { t = blk - 64;  src = Wz; srcN = 256;  dstoff = W_BCZX; dstK = 256;
                              n0 = 1024 + (t >> 2) * 64; sc0 = (t >> 2) * 64; k0 = (t & 3) * 64; }
        else if (blk < 96)  { t = blk - 80;  src = Wx; srcN = 256;  dstoff = W_BCZX; dstK = 256;
                              n0 = 1280 + (t >> 2) * 64; sc0 = (t >> 2) * 64; k0 = (t & 3) * 64; }
        else if (blk < 112) { t = blk - 96;  src = Wo; srcN = 256;  dstoff = W_OUT;  dstK = 256;
                              n0 = (t >> 2) * 64;        sc0 = n0; k0 = (t & 3) * 64; }
        else if (blk < 176) { t = blk - 112; src = Wg; srcN = 1024; dstoff = W_GU;   dstK = 256;
                              n0 = (t >> 2) * 64;        sc0 = n0; k0 = (t & 3) * 64; }
        else if (blk < 240) { t = blk - 176; src = Wu; srcN = 1024; dstoff = W_GU;   dstK = 256;
                              n0 = 1024 + (t >> 2) * 64; sc0 = (t >> 2) * 64; k0 = (t & 3) * 64; }
        else                { t = blk - 240; src = Wd; srcN = 256;  dstoff = W_D;    dstK = 1024;
                              n0 = (t >> 4) * 64;        sc0 = n0; k0 = (t & 15) * 64; }
        if (mix) {
            int h = n0 >> 7, scol = n0 & 127;
            float mm[4];
            #pragma unroll
            for (int g = 0; g < 4; g++) {
                float s = 0.f;
                #pragma unroll
                for (int j = 0; j < 4; j++) s += U[h * 4 + j] * V[g * 4 + j];
                mm[g] = s;
            }
            #pragma unroll
            for (int i = 0; i < 16; i++) {
                int idx = tid + i * 256;
                int kk = idx >> 6, nn = idx & 63;
                const float* row = src + (size_t)(k0 + kk) * 512 + scol + nn;
                lds[kk * 65 + nn] = mm[0] * row[0] + mm[1] * row[128]
                                  + mm[2] * row[256] + mm[3] * row[384];
            }
        } else {
            #pragma unroll
            for (int i = 0; i < 16; i++) {
                int idx = tid + i * 256;
                int kk = idx >> 6, nn = idx & 63;
                lds[kk * 65 + nn] = src[(size_t)(k0 + kk) * srcN + sc0 + nn];
            }
        }
        __syncthreads();
        #pragma unroll
        for (int i = 0; i < 16; i++) {
            int idx = tid + i * 256;
            int nn = idx >> 6, kk = idx & 63;
            wout[dstoff + (size_t)(n0 + nn) * dstK + k0 + kk] = f2bits(lds[kk * 65 + nn]);
        }
        return;
    }
    // ---- LN1 + dt path ----
    int r = blk - 368;
    float* lds = smem;          // 4 floats
    float* dts = smem + 4;      // 16 floats
    int t = r & 255, bk = r >> 8;
    int b_ = bk >> 3, k = bk & 7;
    int srcr = ((b_ * 256 + t) * 8 + k) * 256;
    int d = tid;
    float x = z[srcr + d];
    float v = x;
    #pragma unroll
    for (int off = 32; off; off >>= 1) v += __shfl_xor(v, off, 64);
    if ((d & 63) == 0) lds[d >> 6] = v;
    __syncthreads();
    float mean = (lds[0] + lds[1] + lds[2] + lds[3]) * (1.f / 256.f);
    __syncthreads();
    float c = x - mean;
    v = c * c;
    #pragma unroll
    for (int off = 32; off; off >>= 1) v += __shfl_xor(v, off, 64);
    if ((d & 63) == 0) lds[d >> 6] = v;
    __syncthreads();
    float var = (lds[0] + lds[1] + lds[2] + lds[3]) * (1.f / 256.f);
    float uval = c * rsqrtf(var + 1e-5f) * g1[d] + b1[d];
    u[r * 256 + d] = f2bits(uval);
    float4 wv = *(const float4*)(Wdt + d * 4);
    float q0 = uval * wv.x, q1 = uval * wv.y, q2 = uval * wv.z, q3 = uval * wv.w;
    #pragma unroll
    for (int off = 32; off; off >>= 1) {
        q0 += __shfl_xor(q0, off, 64);
        q1 += __shfl_xor(q1, off, 64);
        q2 += __shfl_xor(q2, off, 64);
        q3 += __shfl_xor(q3, off, 64);
    }
    if ((d & 63) == 0) {
        int w = d >> 6;
        dts[w * 4 + 0] = q0; dts[w * 4 + 1] = q1;
        dts[w * 4 + 2] = q2; dts[w * 4 + 3] = q3;
    }
    __syncthreads();
    if (d == 0) {
        float dv[4];
        #pragma unroll
        for (int h = 0; h < 4; h++) {
            float xx = dts[h] + dts[4 + h] + dts[8 + h] + dts[12 + h] + dt_bias[h];
            dv[h] = (xx > 20.f) ? xx : log1pf(__expf(xx));
        }
        dtv4[r] = make_float4(dv[0], dv[1], dv[2], dv[3]);
    }
}

// ---------------- mega GEMM BCZX: N=1536, pipelined, x out bf16 ----------------
__global__ __launch_bounds__(256) void gemm_bczx(
    const unsigned short* __restrict__ A, const unsigned short* __restrict__ Bt,
    unsigned short* __restrict__ bmb, unsigned short* __restrict__ cmb,
    unsigned short* __restrict__ zgb, unsigned short* __restrict__ xb)
{
    __shared__ unsigned short As[128 * 40];
    __shared__ unsigned short Bs[128 * 40];
    const int K = 256;
    int tid = threadIdx.x;
    int n0 = blockIdx.x * 128, m0 = blockIdx.y * 128;
    int w = tid >> 6, l = tid & 63;
    int mwave = (w >> 1) * 64, nwave = (w & 1) * 64;
    f32x4 acc[4][4] = {};
    int srow = tid >> 2, sc = (tid & 3) * 8;
    const unsigned short* Ap = A + (size_t)(m0 + srow) * K + sc;
    const unsigned short* Bp = Bt + (size_t)(n0 + srow) * K + sc;
    int lq = l & 15, lh = l >> 4, ko = lh * 8;
    uint4 a0 = *(const uint4*)(Ap);
    uint4 a1 = *(const uint4*)(Ap + (size_t)64 * K);
    uint4 b0 = *(const uint4*)(Bp);
    uint4 b1 = *(const uint4*)(Bp + (size_t)64 * K);
    for (int k0 = 0; k0 < K; k0 += 32) {
        if (k0) __syncthreads();
        *(uint4*)&As[srow * 40 + sc] = a0;
        *(uint4*)&As[(srow + 64) * 40 + sc] = a1;
        *(uint4*)&Bs[srow * 40 + sc] = b0;
        *(uint4*)&Bs[(srow + 64) * 40 + sc] = b1;
        __syncthreads();
        if (k0 + 32 < K) {
            a0 = *(const uint4*)(Ap + k0 + 32);
            a1 = *(const uint4*)(Ap + (size_t)64 * K + k0 + 32);
            b0 = *(const uint4*)(Bp + k0 + 32);
            b1 = *(const uint4*)(Bp + (size_t)64 * K + k0 + 32);
        }
        s16x8 bfr[4];
        #pragma unroll
        for (int nf = 0; nf < 4; nf++)
            bfr[nf] = *(const s16x8*)&Bs[(nwave + nf * 16 + lq) * 40 + ko];
        #pragma unroll
        for (int mf = 0; mf < 4; mf++) {
            s16x8 af = *(const s16x8*)&As[(mwave + mf * 16 + lq) * 40 + ko];
            #pragma unroll
            for (int nf = 0; nf < 4; nf++)
                acc[mf][nf] = __builtin_amdgcn_mfma_f32_16x16x32_bf16(af, bfr[nf], acc[mf][nf], 0, 0, 0);
        }
    }
    #pragma unroll
    for (int mf = 0; mf < 4; mf++) {
        #pragma unroll
        for (int nf = 0; nf < 4; nf++) {
            int n = n0 + nwave + nf * 16 + lq;
            #pragma unroll
            for (int r = 0; r < 4; r++) {
                int m = m0 + mwave + mf * 16 + lh * 4 + r;
                float v = acc[mf][nf][r];
                if (n < 512)       bmb[(size_t)m * 512 + n] = f2bits(v);
                else if (n < 1024) cmb[(size_t)m * 512 + (n - 512)] = f2bits(v);
                else if (n < 1280) zgb[(size_t)m * 256 + (n - 1024)] = f2bits(siluf(v));
                else               xb[(size_t)m * 256 + (n - 1280)] = f2bits(v);
            }
        }
    }
}

// ======== combo2: gemm_s (blocks 0..191) + conv_t (blocks 192..447) ========
__global__ __launch_bounds__(256) void s_conv_kernel(
    const unsigned short* __restrict__ cmb, const unsigned short* __restrict__ bmb,
    const float4* __restrict__ dtv4, const float* __restrict__ A_log,
    const float* __restrict__ theta, unsigned short* __restrict__ P,
    const unsigned short* __restrict__ xb, const float* __restrict__ cw,
    unsigned short* __restrict__ x2t)
{
    __shared__ __align__(16) char smem[23808];
    int blk = blockIdx.x;
    int tid = threadIdx.x;
    if (blk >= 192) {
        // ---- conv path ----
        int c = blk - 192;
        int bhid = c >> 2, tt = c & 3;
        int bk = bhid >> 2, h = bhid & 3;
        int t0 = tt * 64;
        float* tile = (float*)smem;     // 67*65 floats
        #pragma unroll
        for (int i = 0; i < 17; i++) {
            int idx = tid + i * 256;
            if (idx < 67 * 64) {
                int tr = idx >> 6, dd = idx & 63;
                int t = t0 - 3 + tr;
                tile[tr * 65 + dd] = (t >= 0)
                    ? bits2f(xb[(size_t)(bk * 256 + t) * 256 + h * 64 + dd]) : 0.f;
            }
        }
        __syncthreads();
        int wv_ = tid >> 6, lt = tid & 63;
        #pragma unroll 4
        for (int pi = 0; pi < 16; pi++) {
            int p = wv_ * 16 + pi;
            float4 wv = *(const float4*)(cw + (h * 64 + p) * 4);
            float acc = tile[lt * 65 + p] * wv.x + tile[(lt + 1) * 65 + p] * wv.y +
                        tile[(lt + 2) * 65 + p] * wv.z + tile[(lt + 3) * 65 + p] * wv.w;
            x2t[(size_t)(bhid * 64 + p) * 256 + t0 + lt] = f2bits(siluf(acc));
        }
        return;
    }
    // ---- gemm_s path ----
    int map = blk >> 6;              // 0,1,2
    int bh = blk & 63;
    int bx = (map == 2) ? 1 : 0;
    int by = (map == 0) ? 0 : 1;
    int bk = bh >> 2, h = bh & 3;
    unsigned short* As = (unsigned short*)smem;            // 128*40
    unsigned short* Bs = As + 128 * 40;                    // 128*40
    float* mAs = (float*)(smem + 20480);                   // 256
    float* phs = mAs + 256;
    float* dss = phs + 256;
    {
        float4 dv = dtv4[bk * 256 + tid];
        float dth = (h == 0) ? dv.x : (h == 1) ? dv.y : (h == 2) ? dv.z : dv.w;
        float Ah = -__expf(A_log[h]);
        float th = theta[h];
        dss[tid] = dth;
        mAs[tid] = dth * Ah;
        phs[tid] = dth * th;
        __syncthreads();
        for (int off = 1; off < 256; off <<= 1) {
            float a = 0.f, p = 0.f;
            int use = (tid >= off);
            if (use) { a = mAs[tid - off]; p = phs[tid - off]; }
            __syncthreads();
            if (use) { mAs[tid] += a; phs[tid] += p; }
            __syncthreads();
        }
    }
    int w = tid >> 6, l = tid & 63;
    int mwave = (w >> 1) * 64, nwave = (w & 1) * 64;
    int lq = l & 15, lh = l >> 4, ko = lh * 8;
    unsigned short* Pout = P + (size_t)bh * 65536;
    f32x4 acc[4][4] = {};
    int srow = tid >> 2, sc = (tid & 3) * 8;
    const unsigned short* Ap = cmb + (size_t)(bk * 256 + by * 128 + srow) * 512 + h * 128 + sc;
    const unsigned short* Bp = bmb + (size_t)(bk * 256 + bx * 128 + srow) * 512 + h * 128 + sc;
    uint4 a0 = *(const uint4*)(Ap);
    uint4 a1 = *(const uint4*)(Ap + (size_t)64 * 512);
    uint4 b0 = *(const uint4*)(Bp);
    uint4 b1 = *(const uint4*)(Bp + (size_t)64 * 512);
    for (int k0 = 0; k0 < 128; k0 += 32) {
        __syncthreads();
        *(uint4*)&As[srow * 40 + sc] = a0;
        *(uint4*)&As[(srow + 64) * 40 + sc] = a1;
        *(uint4*)&Bs[srow * 40 + sc] = b0;
        *(uint4*)&Bs[(srow + 64) * 40 + sc] = b1;
        __syncthreads();
        if (k0 + 32 < 128) {
            a0 = *(const uint4*)(Ap + k0 + 32);
            a1 = *(const uint4*)(Ap + (size_t)64 * 512 + k0 + 32);
            b0 = *(const uint4*)(Bp + k0 + 32);
            b1 = *(const uint4*)(Bp + (size_t)64 * 512 + k0 + 32);
        }
        s16x8 bfr[4];
        #pragma unroll
        for (int nf = 0; nf < 4; nf++)
            bfr[nf] = *(const s16x8*)&Bs[(nwave + nf * 16 + lq) * 40 + ko];
        #pragma unroll
        for (int mf = 0; mf < 4; mf++) {
            s16x8 af = *(const s16x8*)&As[(mwave + mf * 16 + lq) * 40 + ko];
            #pragma unroll
            for (int nf = 0; nf < 4; nf++)
                acc[mf][nf] = __builtin_amdgcn_mfma_f32_16x16x32_bf16(af, bfr[nf], acc[mf][nf], 0, 0, 0);
        }
    }
    #pragma unroll
    for (int mf = 0; mf < 4; mf++) {
        float tmv[4], tpv[4]; int tg[4];
        #pragma unroll
        for (int r = 0; r < 4; r++) {
            tg[r] = by * 128 + mwave + mf * 16 + lh * 4 + r;
            tmv[r] = mAs[tg[r]];
            tpv[r] = phs[tg[r]];
        }
        #pragma unroll
        for (int nf = 0; nf < 4; nf++) {
            int s = bx * 128 + nwave + nf * 16 + lq;
            float ms = mAs[s];
            float ps = phs[s];
            float ds = dss[s];
            #pragma unroll
            for (int r = 0; r < 4; r++) {
                float wgt = (s <= tg[r])
                    ? __expf(tmv[r] - ms) * __cosf(tpv[r] - ps) * ds : 0.f;
                Pout[tg[r] * 256 + s] = f2bits(acc[mf][nf][r] * wgt);
            }
        }
    }
}

// ------- batched Y = P @ X^T (64x64, triangular K-clip, pipelined) + skip+gate -------
__global__ __launch_bounds__(256) void gemm_y(
    const unsigned short* __restrict__ P, const unsigned short* __restrict__ x2t,
    const unsigned short* __restrict__ zgb, const float* __restrict__ Dsk,
    unsigned short* __restrict__ ygb)
{
    int by = blockIdx.x, bh = blockIdx.y;
    int bk = bh >> 2, h = bh & 3;
    int tid = threadIdx.x;
    int w = tid >> 6, l = tid & 63;
    int mw = (w >> 1) * 32, nw = (w & 1) * 32;
    int lq = l & 15, lh = l >> 4, ko = lh * 8;
    __shared__ unsigned short As[64 * 40];
    __shared__ unsigned short Bs[64 * 40];
    f32x4 acc[2][2] = {};
    int srow = tid >> 2, sc = (tid & 3) * 8;
    const unsigned short* Ap = P + (size_t)bh * 65536 + (size_t)(by * 64 + srow) * 256 + sc;
    const unsigned short* Bp = x2t + (size_t)bh * 16384 + (size_t)srow * 256 + sc;
    int kmax = (by + 1) * 64; if (kmax > 256) kmax = 256;
    uint4 a0 = *(const uint4*)(Ap);
    uint4 b0 = *(const uint4*)(Bp);
    for (int k0 = 0; k0 < kmax; k0 += 32) {
        if (k0) __syncthreads();
        *(uint4*)&As[srow * 40 + sc] = a0;
        *(uint4*)&Bs[srow * 40 + sc] = b0;
        __syncthreads();
        if (k0 + 32 < kmax) {
            a0 = *(const uint4*)(Ap + k0 + 32);
            b0 = *(const uint4*)(Bp + k0 + 32);
        }
        s16x8 bfr[2];
        #pragma unroll
        for (int nf = 0; nf < 2; nf++)
            bfr[nf] = *(const s16x8*)&Bs[(nw + nf * 16 + lq) * 40 + ko];
        #pragma unroll
        for (int mf = 0; mf < 2; mf++) {
            s16x8 af = *(const s16x8*)&As[(mw + mf * 16 + lq) * 40 + ko];
            #pragma unroll
            for (int nf = 0; nf < 2; nf++)
                acc[mf][nf] = __builtin_amdgcn_mfma_f32_16x16x32_bf16(af, bfr[nf], acc[mf][nf], 0, 0, 0);
        }
    }
    float dsk = Dsk[h];
    #pragma unroll
    for (int mf = 0; mf < 2; mf++) {
        #pragma unroll
        for (int nf = 0; nf < 2; nf++) {
            int p = nw + nf * 16 + lq;
            #pragma unroll
            for (int r = 0; r < 4; r++) {
                int t = by * 64 + mw + mf * 16 + lh * 4 + r;
                float xv = bits2f(x2t[(size_t)bh * 16384 + p * 256 + t]);
                float zg = bits2f(zgb[(size_t)(bk * 256 + t) * 256 + h * 64 + p]);
                ygb[(size_t)(bk * 256 + t) * 256 + h * 64 + p] =
                    f2bits((acc[mf][nf][r] + dsk * xv) * zg);
            }
        }
    }
}

// ---- fused GEMM(16x256) + bias + residual + LayerNorm epilogue, 256 blocks ----
__global__ __launch_bounds__(256) void gemm_ln(
    const unsigned short* __restrict__ A, const unsigned short* __restrict__ Bt,
    const float* __restrict__ bias, const float* __restrict__ resid,
    const float* __restrict__ g, const float* __restrict__ b,
    float* __restrict__ zfull, unsigned short* __restrict__ znorm, int rowmap)
{
    const int K = 256;
    __shared__ unsigned short As[16 * 40];
    __shared__ unsigned short Bs[256 * 40];
    __shared__ float partS[16][4], partQ[16][4];
    int tid = threadIdx.x;
    int m0 = blockIdx.x * 16;
    int w = tid >> 6, l = tid & 63;
    int nw = w * 64;
    int lq = l & 15, lh = l >> 4, ko = lh * 8;
    f32x4 acc[4] = {};
    int srow = tid >> 2, sc = (tid & 3) * 8;
    const unsigned short* Ap = A + (size_t)(m0 + (srow & 15)) * K + sc;
    const unsigned short* Bp = Bt + (size_t)srow * K + sc;
    uint4 a0 = *(const uint4*)(Ap);
    uint4 b0 = *(const uint4*)(Bp);
    uint4 b1 = *(const uint4*)(Bp + (size_t)64 * K);
    uint4 b2 = *(const uint4*)(Bp + (size_t)128 * K);
    uint4 b3 = *(const uint4*)(Bp + (size_t)192 * K);
    for (int k0 = 0; k0 < K; k0 += 32) {
        if (k0) __syncthreads();
        if (tid < 64) *(uint4*)&As[srow * 40 + sc] = a0;
        *(uint4*)&Bs[srow * 40 + sc] = b0;
        *(uint4*)&Bs[(srow + 64) * 40 + sc] = b1;
        *(uint4*)&Bs[(srow + 128) * 40 + sc] = b2;
        *(uint4*)&Bs[(srow + 192) * 40 + sc] = b3;
        __syncthreads();
        if (k0 + 32 < K) {
            a0 = *(const uint4*)(Ap + k0 + 32);
            b0 = *(const uint4*)(Bp + k0 + 32);
            b1 = *(const uint4*)(Bp + (size_t)64 * K + k0 + 32);
            b2 = *(const uint4*)(Bp + (size_t)128 * K + k0 + 32);
            b3 = *(const uint4*)(Bp + (size_t)192 * K + k0 + 32);
        }
        s16x8 af = *(const s16x8*)&As[lq * 40 + ko];
        #pragma unroll
        for (int nf = 0; nf < 4; nf++) {
            s16x8 bf = *(const s16x8*)&Bs[(nw + nf * 16 + lq) * 40 + ko];
            acc[nf] = __builtin_amdgcn_mfma_f32_16x16x32_bf16(af, bf, acc[nf], 0, 0, 0);
        }
    }
    float bv[4];
    #pragma unroll
    for (int nf = 0; nf < 4; nf++) bv[nf] = bias ? bias[nw + nf * 16 + lq] : 0.f;
    int orow[4];
    #pragma unroll
    for (int r = 0; r < 4; r++) {
        int rb = m0 + lh * 4 + r;
        if (rowmap) {
            int bk = rb >> 8, t = rb & 255;
            orow[r] = ((bk >> 3) * 256 + t) * 8 + (bk & 7);
        } else orow[r] = rb;
    }
    #pragma unroll
    for (int r = 0; r < 4; r++) {
        float s = 0.f, q = 0.f;
        #pragma unroll
        for (int nf = 0; nf < 4; nf++) {
            float v = acc[nf][r] + bv[nf]
                    + resid[(size_t)orow[r] * 256 + nw + nf * 16 + lq];
            acc[nf][r] = v;
            s += v; q += v * v;
        }
        #pragma unroll
        for (int off = 1; off < 16; off <<= 1) {
            s += __shfl_xor(s, off, 64);
            q += __shfl_xor(q, off, 64);
        }
        if (lq == 0) {
            int row = lh * 4 + r;
            partS[row][w] = s; partQ[row][w] = q;
        }
    }
    __syncthreads();
    float gv[4], bbv[4];
    #pragma unroll
    for (int nf = 0; nf < 4; nf++) {
        gv[nf] = g[nw + nf * 16 + lq];
        bbv[nf] = b[nw + nf * 16 + lq];
    }
    #pragma unroll
    for (int r = 0; r < 4; r++) {
        int row = lh * 4 + r;
        float sum = partS[row][0] + partS[row][1] + partS[row][2] + partS[row][3];
        float sq  = partQ[row][0] + partQ[row][1] + partQ[row][2] + partQ[row][3];
        float mean = sum * (1.f / 256.f);
        float var = sq * (1.f / 256.f) - mean * mean;
        float rstd = rsqrtf(var + 1e-5f);
        size_t ro = (size_t)orow[r] * 256;
        #pragma unroll
        for (int nf = 0; nf < 4; nf++) {
            int n = nw + nf * 16 + lq;
            float v = acc[nf][r];
            zfull[ro + n] = v;
            znorm[ro + n] = f2bits((v - mean) * rstd * gv[nf] + bbv[nf]);
        }
    }
}

// ---------------- generic MFMA bf16 GEMM (128x128 tile, pipelined) ----------------
__global__ __launch_bounds__(256) void mfma_gemm(
    const unsigned short* __restrict__ A, const unsigned short* __restrict__ Bt,
    const float* __restrict__ bias, void* __restrict__ C,
    int N, int K, int out_bf16)
{
    __shared__ unsigned short As[128 * 40];
    __shared__ unsigned short Bs[128 * 40];
    int tid = threadIdx.x;
    int n0 = blockIdx.x * 128, m0 = blockIdx.y * 128;
    int w = tid >> 6, l = tid & 63;
    int mwave = (w >> 1) * 64, nwave = (w & 1) * 64;
    f32x4 acc[4][4] = {};
    int srow = tid >> 2, sc = (tid & 3) * 8;
    const unsigned short* Ap = A + (size_t)(m0 + srow) * K + sc;
    const unsigned short* Bp = Bt + (size_t)(n0 + srow) * K + sc;
    int lq = l & 15, lh = l >> 4, ko = lh * 8;
    uint4 a0 = *(const uint4*)(Ap);
    uint4 a1 = *(const uint4*)(Ap + (size_t)64 * K);
    uint4 b0 = *(const uint4*)(Bp);
    uint4 b1 = *(const uint4*)(Bp + (size_t)64 * K);
    for (int k0 = 0; k0 < K; k0 += 32) {
        if (k0) __syncthreads();
        *(uint4*)&As[srow * 40 + sc] = a0;
        *(uint4*)&As[(srow + 64) * 40 + sc] = a1;
        *(uint4*)&Bs[srow * 40 + sc] = b0;
        *(uint4*)&Bs[(srow + 64) * 40 + sc] = b1;
        __syncthreads();
        if (k0 + 32 < K) {
            a0 = *(const uint4*)(Ap + k0 + 32);
            a1 = *(const uint4*)(Ap + (size_t)64 * K + k0 + 32);
            b0 = *(const uint4*)(Bp + k0 + 32);
            b1 = *(const uint4*)(Bp + (size_t)64 * K + k0 + 32);
        }
        s16x8 bfr[4];
        #pragma unroll
        for (int nf = 0; nf < 4; nf++)
            bfr[nf] = *(const s16x8*)&Bs[(nwave + nf * 16 + lq) * 40 + ko];
        #pragma unroll
        for (int mf = 0; mf < 4; mf++) {
            s16x8 af = *(const s16x8*)&As[(mwave + mf * 16 + lq) * 40 + ko];
            #pragma unroll
            for (int nf = 0; nf < 4; nf++)
                acc[mf][nf] = __builtin_amdgcn_mfma_f32_16x16x32_bf16(af, bfr[nf], acc[mf][nf], 0, 0, 0);
        }
    }
    #pragma unroll
    for (int mf = 0; mf < 4; mf++) {
        #pragma unroll
        for (int nf = 0; nf < 4; nf++) {
            int n = n0 + nwave + nf * 16 + lq;
            float bs_ = bias ? bias[n] : 0.f;
            #pragma unroll
            for (int r = 0; r < 4; r++) {
                int m = m0 + mwave + mf * 16 + lh * 4 + r;
                float v = acc[mf][nf][r] + bs_;
                if (out_bf16) ((unsigned short*)C)[(size_t)m * N + n] = f2bits(v);
                else          ((float*)C)[(size_t)m * N + n] = v;
            }
        }
    }
}

// ---- gemm_gu2: dual-accumulator G/U with fused silu(g)*u -> gg bf16 [4096,1024] ----
__global__ __launch_bounds__(256) void gemm_gu2(
    const unsigned short* __restrict__ A, const unsigned short* __restrict__ Wgu,
    unsigned short* __restrict__ gg)
{
    const int K = 256;
    __shared__ unsigned short As[128 * 40];
    __shared__ unsigned short Bgs[64 * 40];
    __shared__ unsigned short Bus[64 * 40];
    int tid = threadIdx.x;
    int n0 = blockIdx.x * 64, m0 = blockIdx.y * 128;
    int w = tid >> 6, l = tid & 63;
    int mwave = (w >> 1) * 64, nwave = (w & 1) * 32;
    int lq = l & 15, lh = l >> 4, ko = lh * 8;
    f32x4 ag[4][2] = {}, au[4][2] = {};
    int srow = tid >> 2, sc = (tid & 3) * 8;
    const unsigned short* Ap = A + (size_t)(m0 + srow) * K + sc;
    const unsigned short* Bgp = Wgu + (size_t)(n0 + srow) * K + sc;
    const unsigned short* Bup = Wgu + (size_t)(1024 + n0 + srow) * K + sc;
    uint4 a0 = *(const uint4*)(Ap);
    uint4 a1 = *(const uint4*)(Ap + (size_t)64 * K);
    uint4 bg = *(const uint4*)(Bgp);
    uint4 bu = *(const uint4*)(Bup);
    for (int k0 = 0; k0 < K; k0 += 32) {
        if (k0) __syncthreads();
        *(uint4*)&As[srow * 40 + sc] = a0;
        *(uint4*)&As[(srow + 64) * 40 + sc] = a1;
        *(uint4*)&Bgs[srow * 40 + sc] = bg;
        *(uint4*)&Bus[srow * 40 + sc] = bu;
        __syncthreads();
        if (k0 + 32 < K) {
            a0 = *(const uint4*)(Ap + k0 + 32);
            a1 = *(const uint4*)(Ap + (size_t)64 * K + k0 + 32);
            bg = *(const uint4*)(Bgp + k0 + 32);
            bu = *(const uint4*)(Bup + k0 + 32);
        }
        s16x8 bgr[2], bur[2];
        #pragma unroll
        for (int nf = 0; nf < 2; nf++) {
            bgr[nf] = *(const s16x8*)&Bgs[(nwave + nf * 16 + lq) * 40 + ko];
            bur[nf] = *(const s16x8*)&Bus[(nwave + nf * 16 + lq) * 40 + ko];
        }
        #pragma unroll
        for (int mf = 0; mf < 4; mf++) {
            s16x8 af = *(const s16x8*)&As[(mwave + mf * 16 + lq) * 40 + ko];
            #pragma unroll
            for (int nf = 0; nf < 2; nf++) {
                ag[mf][nf] = __builtin_amdgcn_mfma_f32_16x16x32_bf16(af, bgr[nf], ag[mf][nf], 0, 0, 0);
                au[mf][nf] = __builtin_amdgcn_mfma_f32_16x16x32_bf16(af, bur[nf], au[mf][nf], 0, 0, 0);
            }
        }
    }
    #pragma unroll
    for (int mf = 0; mf < 4; mf++) {
        #pragma unroll
        for (int nf = 0; nf < 2; nf++) {
            int n = n0 + nwave + nf * 16 + lq;
            #pragma unroll
            for (int r = 0; r < 4; r++) {
                int m = m0 + mwave + mf * 16 + lh * 4 + r;
                gg[(size_t)m * 1024 + n] = f2bits(siluf(ag[mf][nf][r]) * au[mf][nf][r]);
            }
        }
    }
}

// ------- gemm_d2 (64x64, pipelined): out = gg @ Wd^T + resid (fp32) -------
__global__ __launch_bounds__(256) void gemm_d2(
    const unsigned short* __restrict__ gg, const unsigned short* __restrict__ Bt,
    const float* __restrict__ resid, float* __restrict__ out)
{
    __shared__ unsigned short As[64 * 40];
    __shared__ unsigned short Bs[64 * 40];
    const int K = 1024, N = 256;
    int tid = threadIdx.x;
    int n0 = blockIdx.x * 64, m0 = blockIdx.y * 64;
    int w = tid >> 6, l = tid & 63;
    int mw = (w >> 1) * 32, nw = (w & 1) * 32;
    f32x4 acc[2][2] = {};
    int srow = tid >> 2, sc = (tid & 3) * 8;
    const unsigned short* Ap = gg + (size_t)(m0 + srow) * K + sc;
    const unsigned short* Bp = Bt + (size_t)(n0 + srow) * K + sc;
    int lq = l & 15, lh = l >> 4, ko = lh * 8;
    uint4 a0 = *(const uint4*)(Ap);
    uint4 b0 = *(const uint4*)(Bp);
    for (int k0 = 0; k0 < K; k0 += 32) {
        if (k0) __syncthreads();
        *(uint4*)&As[srow * 40 + sc] = a0;
        *(uint4*)&Bs[srow * 40 + sc] = b0;
        __syncthreads();
        if (k0 + 32 < K) {
            a0 = *(const uint4*)(Ap + k0 + 32);
            b0 = *(const uint4*)(Bp + k0 + 32);
        }
        s16x8 bfr[2];
        #pragma unroll
        for (int nf = 0; nf < 2; nf++)
            bfr[nf] = *(const s16x8*)&Bs[(nw + nf * 16 + lq) * 40 + ko];
        #pragma unroll
        for (int mf = 0; mf < 2; mf++) {
            s16x8 af = *(const s16x8*)&As[(mw + mf * 16 + lq) * 40 + ko];
            #pragma unroll
            for (int nf = 0; nf < 2; nf++)
                acc[mf][nf] = __builtin_amdgcn_mfma_f32_16x16x32_bf16(af, bfr[nf], acc[mf][nf], 0, 0, 0);
        }
    }
    #pragma unroll
    for (int mf = 0; mf < 2; mf++) {
        #pragma unroll
        for (int nf = 0; nf < 2; nf++) {
            int n = n0 + nw + nf * 16 + lq;
            #pragma unroll
            for (int r = 0; r < 4; r++) {
                int m = m0 + mw + mf * 16 + lh * 4 + r;
                out[(size_t)m * N + n] = acc[mf][nf][r] + resid[(size_t)m * N + n];
            }
        }
    }
}

// ---------------- windowed attention (bf16 in/out) ----------------
__global__ __launch_bounds__(256) void attn_kernel(const unsigned short* __restrict__ qkv,
    unsigned short* __restrict__ o)
{
    int m = blockIdx.x >> 1, w = blockIdx.x & 1;
    int tid = threadIdx.x;
    int h = tid >> 6, d = tid & 63;
    __shared__ float qs[4][256], ks[4][256], vs[4][256];
    #pragma unroll
    for (int j = 0; j < 4; j++) {
        int row = m * 8 + w * 4 + j;
        int base = row * 768;
        qs[j][tid] = bits2f(qkv[base + tid]);
        ks[j][tid] = bits2f(qkv[base + 256 + tid]);
        vs[j][tid] = bits2f(qkv[base + 512 + tid]);
    }
    __syncthreads();
    float sc[4][4];
    #pragma unroll
    for (int qi = 0; qi < 4; qi++)
        #pragma unroll
        for (int ki = 0; ki < 4; ki++) {
            float v = qs[qi][h * 64 + d] * ks[ki][h * 64 + d];
            #pragma unroll
            for (int off = 32; off; off >>= 1) v += __shfl_xor(v, off, 64);
            sc[qi][ki] = v * 0.125f;
        }
    #pragma unroll
    for (int qi = 0; qi < 4; qi++) {
        float mx = fmaxf(fmaxf(sc[qi][0], sc[qi][1]), fmaxf(sc[qi][2], sc[qi][3]));
        float e0 = __expf(sc[qi][0] - mx), e1 = __expf(sc[qi][1] - mx);
        float e2 = __expf(sc[qi][2] - mx), e3 = __expf(sc[qi][3] - mx);
        float inv = 1.f / (e0 + e1 + e2 + e3);
        float ov = (e0 * vs[0][h * 64 + d] + e1 * vs[1][h * 64 + d] +
                    e2 * vs[2][h * 64 + d] + e3 * vs[3][h * 64 + d]) * inv;
        o[(m * 8 + w * 4 + qi) * 256 + h * 64 + d] = f2bits(ov);
    }
}

extern "C" void kernel_launch(void* const* d_in, const int* in_sizes, int n_in,
                              void* d_out, int out_size, void* d_ws, size_t ws_size,
                              hipStream_t stream)
{
    const float* z         = (const float*)d_in[0];
    const float* ln1_g     = (const float*)d_in[1];
    const float* ln1_b     = (const float*)d_in[2];
    const float* Wx        = (const float*)d_in[3];
    const float* conv_w    = (const float*)d_in[4];
    const float* Wz        = (const float*)d_in[5];
    const float* Wb        = (const float*)d_in[6];
    const float* Wc        = (const float*)d_in[7];
    const float* Wdt       = (const float*)d_in[8];
    const float* dt_bias   = (const float*)d_in[9];
    const float* A_log     = (const float*)d_in[10];
    const float* theta     = (const float*)d_in[11];
    const float* D_skip    = (const float*)d_in[12];
    const float* mimo_U    = (const float*)d_in[13];
    const float* mimo_V    = (const float*)d_in[14];
    const float* Wout      = (const float*)d_in[15];
    const float* ln2_g     = (const float*)d_in[16];
    const float* ln2_b     = (const float*)d_in[17];
    const float* attn_in_w = (const float*)d_in[18];
    const float* attn_in_b = (const float*)d_in[19];
    const float* attn_out_w= (const float*)d_in[20];
    const float* attn_out_b= (const float*)d_in[21];
    const float* ln3_g     = (const float*)d_in[22];
    const float* ln3_b     = (const float*)d_in[23];
    const float* Wg        = (const float*)d_in[24];
    const float* Wu        = (const float*)d_in[25];
    const float* Wd        = (const float*)d_in[26];

    float* W = (float*)d_ws;
    unsigned short* wts = (unsigned short*)W;
    unsigned short* ub  = (unsigned short*)(W + OFF_UB);
    float4* dtv4        = (float4*)(W + OFF_DTV);
    unsigned short* bmb = (unsigned short*)(W + OFF_BMB);
    unsigned short* cmb = (unsigned short*)(W + OFF_CMB);
    unsigned short* zgb = (unsigned short*)(W + OFF_ZGB);
    unsigned short* xb  = (unsigned short*)(W + OFF_XB);
    unsigned short* x2t = (unsigned short*)(W + OFF_X2T);
    unsigned short* pbuf= (unsigned short*)(W + OFF_P);
    unsigned short* ygb = (unsigned short*)(W + OFF_YGB);
    float* z1           = W + OFF_Z1;
    unsigned short* znb = (unsigned short*)(W + OFF_ZNB);
    unsigned short* qkvb= (unsigned short*)(W + OFF_QKV);
    unsigned short* ob  = (unsigned short*)(W + OFF_OB);
    float* z2           = W + OFF_Z2;
    unsigned short* zfb = (unsigned short*)(W + OFF_ZFB);
    unsigned short* gg  = (unsigned short*)(W + OFF_GG);

    prep_ln1_kernel<<<4464, 256, 0, stream>>>(
        Wx, Wb, Wc, Wz, Wout, attn_in_w, attn_out_w, Wg, Wu, Wd, mimo_U, mimo_V,
        wts, z, ln1_g, ln1_b, Wdt, dt_bias, ub, dtv4);
    gemm_bczx<<<dim3(12, 32), 256, 0, stream>>>(ub, wts + W_BCZX, bmb, cmb, zgb, xb);
    s_conv_kernel<<<448, 256, 0, stream>>>(cmb, bmb, dtv4, A_log, theta, pbuf,
                                           xb, conv_w, x2t);
    gemm_y<<<dim3(4, 64), 256, 0, stream>>>(pbuf, x2t, zgb, D_skip, ygb);
    gemm_ln<<<256, 256, 0, stream>>>(ygb, wts + W_OUT, nullptr, z, ln2_g, ln2_b,
                                     z1, znb, 1);
    mfma_gemm<<<dim3(6, 32), 256, 0, stream>>>(znb, wts + W_QKV, attn_in_b, qkvb, 768, 256, 1);
    attn_kernel<<<1024, 256, 0, stream>>>(qkvb, ob);
    gemm_ln<<<256, 256, 0, stream>>>(ob, wts + W_AO, attn_out_b, z1, ln3_g, ln3_b,
                                     z2, zfb, 0);
    gemm_gu2<<<dim3(16, 32), 256, 0, stream>>>(zfb, wts + W_GU, gg);
    gemm_d2<<<dim3(4, 64), 256, 0, stream>>>(gg, wts + W_D, z2, (float*)d_out);
}